// Round 8
// baseline (62.384 us; speedup 1.0000x reference)
//
#include <hip/hip_runtime.h>
#include <math.h>

#define K_DIM 2048
#define E_DIM 64
#define BM 32                  // rows per block (grid = 512)
#define NW 4                   // waves per block (256 threads)
#define KC 128                 // K floats staged per chunk
#define NT (K_DIM / KC)        // 16 chunks
#define WSCALE 64.0f           // power-of-2 scale so w_lo stays fp16-normal
#define LGSTRIDE 68

typedef _Float16 f16x8 __attribute__((ext_vector_type(8)));
typedef float    f32x4 __attribute__((ext_vector_type(4)));

__device__ __forceinline__ void load_lds16(const float* g, float* l) {
    __builtin_amdgcn_global_load_lds(
        (const __attribute__((address_space(1))) unsigned int*)(g),
        (__attribute__((address_space(3))) unsigned int*)(l),
        16, 0, 0);
}

// Pack w[e][k] fp32 -> fp16 hi/lo fragment streams in exact MFMA B order:
// frag f = (kk*4 + ntile)*64 + lane ; halves j=0..7 are k = kk*32 + (lane>>4)*8 + j
// of col = ntile*16 + (lane&15). hi at wpk[0..], lo at wpk + K_DIM*E_DIM.
__global__ void pack_w_kernel(const float* __restrict__ w, _Float16* __restrict__ wpk) {
    int tid  = (int)blockIdx.x * 256 + (int)threadIdx.x;   // 16384 threads
    int lane = tid & 63;
    int n    = (tid >> 6) & 3;
    int kk   = tid >> 8;                                   // 0..63
    int col  = n * 16 + (lane & 15);
    int k    = kk * 32 + (lane >> 4) * 8;
    const float* src = w + (size_t)col * K_DIM + k;
    _Float16* hi = wpk + (size_t)tid * 8;
    _Float16* lo = hi + (size_t)K_DIM * E_DIM;
    #pragma unroll
    for (int j = 0; j < 8; ++j) {
        float v = src[j] * WSCALE;
        _Float16 h = (_Float16)v;
        hi[j] = h;
        lo[j] = (_Float16)(v - (float)h);
    }
}

__global__ __launch_bounds__(256, 2) void mfma_gate_kernel(
    const float* __restrict__ x,
    const _Float16* __restrict__ wpk,
    float* __restrict__ out, int M)
{
    // double-buffered x tile: 2 x (32 rows x 128 floats) = 32 KB.
    // Physical layout: stg[b][row*KC + p4*4 + i], where physical float4 index
    // p4 holds logical float4 (p4 ^ (row&7))  [XOR swizzle, involution].
    __shared__ float stg[2][BM * KC];

    const int t    = (int)threadIdx.x;
    const int lane = t & 63;
    const int wave = __builtin_amdgcn_readfirstlane(t >> 6);   // 0..3, = N-tile
    const int lr   = lane & 15;
    const int ks   = lane >> 4;
    const int rowbase = (int)blockIdx.x * BM;

    f32x4 acc[2];
    acc[0] = (f32x4){0.f, 0.f, 0.f, 0.f};
    acc[1] = (f32x4){0.f, 0.f, 0.f, 0.f};

    // staging: wave w issues 4 global_load_lds per chunk, slot = w*4+j covers
    // rows slot*2 .. slot*2+1 (512 B each). lane: row = slot*2 + (lane>>5),
    // physical p4 = lane&31, fetch logical c4 = p4 ^ (row&7).
    const float* gsrc[4];
    #pragma unroll
    for (int j = 0; j < 4; ++j) {
        const int slot = wave * 4 + j;
        const int row  = slot * 2 + (lane >> 5);
        const int c4   = (lane & 31) ^ (row & 7);
        gsrc[j] = x + (size_t)(rowbase + row) * K_DIM + c4 * 4;
    }

    // B stream (this wave's 16-expert slice), packed fragment order
    const _Float16* wph = wpk + (size_t)wave * 512 + (size_t)lane * 8;
    const _Float16* wpl = wph + (size_t)K_DIM * E_DIM;

    // prologue: stage chunk 0
    #pragma unroll
    for (int j = 0; j < 4; ++j)
        load_lds16(gsrc[j], &stg[0][(wave * 4 + j) * 256]);
    __syncthreads();

    #pragma unroll 1
    for (int c = 0; c < NT; ++c) {
        const int cur = c & 1;

        // ---- B loads first (L2; oldest in vmcnt order so their wait
        //      doesn't drain the HBM stage below) ----
        f16x8 bh[4], bl[4];
        #pragma unroll
        for (int s2 = 0; s2 < 4; ++s2) {
            const size_t off = (size_t)((c * 4 + s2) * 4) * 512;
            bh[s2] = *(const f16x8*)(wph + off);
            bl[s2] = *(const f16x8*)(wpl + off);
        }

        // ---- async-stage next chunk into the other buffer ----
        if (c + 1 < NT) {
            #pragma unroll
            for (int j = 0; j < 4; ++j)
                load_lds16(gsrc[j] + (size_t)(c + 1) * KC,
                           &stg[cur ^ 1][(wave * 4 + j) * 256]);
        }

        // ---- compute current chunk from LDS ----
        const float* bufc = stg[cur];
        const int key = lr & 7;
        #pragma unroll
        for (int s2 = 0; s2 < 4; ++s2) {
            #pragma unroll
            for (int m = 0; m < 2; ++m) {
                const int row = m * 16 + lr;
                const int c4a = s2 * 8 + ks * 2;
                float4 a0 = *(const float4*)&bufc[row * KC + ((c4a)     ^ key) * 4];
                float4 a1 = *(const float4*)&bufc[row * KC + ((c4a + 1) ^ key) * 4];
                float u[8] = {a0.x, a0.y, a0.z, a0.w, a1.x, a1.y, a1.z, a1.w};
                f16x8 ah, al;
                #pragma unroll
                for (int j = 0; j < 8; ++j) {
                    _Float16 h = (_Float16)u[j];
                    ah[j] = h;
                    al[j] = (_Float16)(u[j] - (float)h);
                }
                acc[m] = __builtin_amdgcn_mfma_f32_16x16x32_f16(ah, bh[s2], acc[m], 0, 0, 0);
                acc[m] = __builtin_amdgcn_mfma_f32_16x16x32_f16(ah, bl[s2], acc[m], 0, 0, 0);
                acc[m] = __builtin_amdgcn_mfma_f32_16x16x32_f16(al, bh[s2], acc[m], 0, 0, 0);
            }
        }
        __syncthreads();   // drains vmcnt(0) AFTER compute; next buf ready
    }

    // ---- exchange logits via LDS (reuse stg[0]: 32 x 68 floats = 8.5 KB) ----
    float* lg = &stg[0][0];
    const float inv = 1.0f / WSCALE;
    #pragma unroll
    for (int m = 0; m < 2; ++m)
        #pragma unroll
        for (int j = 0; j < 4; ++j)
            lg[(m * 16 + ks * 4 + j) * LGSTRIDE + wave * 16 + lr] = acc[m][j] * inv;
    __syncthreads();

    // ---- gating: each wave finishes 8 rows; lane == expert ----
    #pragma unroll 1
    for (int rr = 0; rr < BM / NW; ++rr) {
        const int r = wave * (BM / NW) + rr;
        float l = lg[r * LGSTRIDE + lane];

        float m = l;
        #pragma unroll
        for (int off = 32; off >= 1; off >>= 1)
            m = fmaxf(m, __shfl_xor(m, off));

        float e = expf(l - m);
        float z = e;
        #pragma unroll
        for (int off = 32; off >= 1; off >>= 1)
            z += __shfl_xor(z, off);
        const float p = e / z;

        float v1 = p; int i1 = lane;
        #pragma unroll
        for (int off = 32; off >= 1; off >>= 1) {
            float ov = __shfl_xor(v1, off);
            int   oi = __shfl_xor(i1, off);
            if (ov > v1 || (ov == v1 && oi < i1)) { v1 = ov; i1 = oi; }
        }

        float v2 = (lane == i1) ? -1.0f : p; int i2 = lane;
        #pragma unroll
        for (int off = 32; off >= 1; off >>= 1) {
            float ov = __shfl_xor(v2, off);
            int   oi = __shfl_xor(i2, off);
            if (ov > v2 || (ov == v2 && oi < i2)) { v2 = ov; i2 = oi; }
        }

        if (lane == 0) {
            const size_t row = (size_t)rowbase + r;
            const float denom = v1 + v2 + 1e-9f;
            out[row * 2 + 0] = v1 / denom;
            out[row * 2 + 1] = v2 / denom;
            out[(size_t)M * 2 + row * 2 + 0] = (float)i1;
            out[(size_t)M * 2 + row * 2 + 1] = (float)i2;
        }
    }
}

// Fallback (ws too small): direct strided B loads, R3-style split-K.
__global__ __launch_bounds__(256, 2) void mfma_gate_kernel_raw(
    const float* __restrict__ x,
    const float* __restrict__ w,
    float* __restrict__ out, int M)
{
    __shared__ float red[4][BM][LGSTRIDE];
    const int t    = (int)threadIdx.x;
    const int lane = t & 63;
    const int wave = __builtin_amdgcn_readfirstlane(t >> 6);
    const int lr   = lane & 15;
    const int ks   = lane >> 4;
    const int rowbase = (int)blockIdx.x * BM;
    const size_t k0 = (size_t)wave * 512;

    f32x4 acc[2][4];
    #pragma unroll
    for (int m = 0; m < 2; ++m)
        #pragma unroll
        for (int n = 0; n < 4; ++n)
            acc[m][n] = (f32x4){0.f, 0.f, 0.f, 0.f};

    const float* xa0 = x + (size_t)(rowbase + lr) * K_DIM + k0 + (size_t)ks * 8;
    const float* xa1 = xa0 + (size_t)16 * K_DIM;

    for (int s = 0; s < 16; ++s) {
        f16x8 ah[2], al[2];
        #pragma unroll
        for (int m = 0; m < 2; ++m) {
            const float* p = (m == 0 ? xa0 : xa1) + (size_t)s * 32;
            float4 u0 = *(const float4*)p;
            float4 u1 = *(const float4*)(p + 4);
            float uu[8] = {u0.x, u0.y, u0.z, u0.w, u1.x, u1.y, u1.z, u1.w};
            #pragma unroll
            for (int j = 0; j < 8; ++j) {
                _Float16 h = (_Float16)uu[j];
                ah[m][j] = h;
                al[m][j] = (_Float16)(uu[j] - (float)h);
            }
        }
        f16x8 bh[4], bl[4];
        #pragma unroll
        for (int n = 0; n < 4; ++n) {
            const float* p = w + (size_t)(n * 16 + lr) * K_DIM + k0 + (size_t)s * 32 + (size_t)ks * 8;
            float4 u0 = *(const float4*)p;
            float4 u1 = *(const float4*)(p + 4);
            float uu[8] = {u0.x, u0.y, u0.z, u0.w, u1.x, u1.y, u1.z, u1.w};
            #pragma unroll
            for (int j = 0; j < 8; ++j) {
                float v = uu[j] * WSCALE;
                _Float16 h = (_Float16)v;
                bh[n][j] = h;
                bl[n][j] = (_Float16)(v - (float)h);
            }
        }
        #pragma unroll
        for (int m = 0; m < 2; ++m)
            #pragma unroll
            for (int n = 0; n < 4; ++n) {
                acc[m][n] = __builtin_amdgcn_mfma_f32_16x16x32_f16(ah[m], bh[n], acc[m][n], 0, 0, 0);
                acc[m][n] = __builtin_amdgcn_mfma_f32_16x16x32_f16(ah[m], bl[n], acc[m][n], 0, 0, 0);
                acc[m][n] = __builtin_amdgcn_mfma_f32_16x16x32_f16(al[m], bh[n], acc[m][n], 0, 0, 0);
            }
    }

    const float inv = 1.0f / WSCALE;
    #pragma unroll
    for (int m = 0; m < 2; ++m)
        #pragma unroll
        for (int n = 0; n < 4; ++n)
            #pragma unroll
            for (int j = 0; j < 4; ++j)
                red[wave][m * 16 + ks * 4 + j][n * 16 + lr] = acc[m][n][j] * inv;
    __syncthreads();

    #pragma unroll 1
    for (int rr = 0; rr < BM / 4; ++rr) {
        const int r = wave * (BM / 4) + rr;
        float l = red[0][r][lane] + red[1][r][lane] + red[2][r][lane] + red[3][r][lane];
        float m = l;
        #pragma unroll
        for (int off = 32; off >= 1; off >>= 1)
            m = fmaxf(m, __shfl_xor(m, off));
        float e = expf(l - m);
        float z = e;
        #pragma unroll
        for (int off = 32; off >= 1; off >>= 1)
            z += __shfl_xor(z, off);
        const float p = e / z;
        float v1 = p; int i1 = lane;
        #pragma unroll
        for (int off = 32; off >= 1; off >>= 1) {
            float ov = __shfl_xor(v1, off);
            int   oi = __shfl_xor(i1, off);
            if (ov > v1 || (ov == v1 && oi < i1)) { v1 = ov; i1 = oi; }
        }
        float v2 = (lane == i1) ? -1.0f : p; int i2 = lane;
        #pragma unroll
        for (int off = 32; off >= 1; off >>= 1) {
            float ov = __shfl_xor(v2, off);
            int   oi = __shfl_xor(i2, off);
            if (ov > v2 || (ov == v2 && oi < i2)) { v2 = ov; i2 = oi; }
        }
        if (lane == 0) {
            const size_t row = (size_t)rowbase + r;
            const float denom = v1 + v2 + 1e-9f;
            out[row * 2 + 0] = v1 / denom;
            out[row * 2 + 1] = v2 / denom;
            out[(size_t)M * 2 + row * 2 + 0] = (float)i1;
            out[(size_t)M * 2 + row * 2 + 1] = (float)i2;
        }
    }
}

extern "C" void kernel_launch(void* const* d_in, const int* in_sizes, int n_in,
                              void* d_out, int out_size, void* d_ws, size_t ws_size,
                              hipStream_t stream)
{
    const float* x = (const float*)d_in[0];
    const float* w = (const float*)d_in[1];
    float* out = (float*)d_out;
    const int M = in_sizes[0] / K_DIM;          // 16384 rows
    const int grid = M / BM;                    // 512 blocks

    const size_t pack_bytes = (size_t)K_DIM * E_DIM * 2 * sizeof(_Float16);  // 512 KB
    if (ws_size >= pack_bytes) {
        pack_w_kernel<<<64, 256, 0, stream>>>(w, (_Float16*)d_ws);
        mfma_gate_kernel<<<grid, 256, 0, stream>>>(x, (const _Float16*)d_ws, out, M);
    } else {
        mfma_gate_kernel_raw<<<grid, 256, 0, stream>>>(x, w, out, M);
    }
}